// Round 5
// baseline (77.239 us; speedup 1.0000x reference)
//
#include <hip/hip_runtime.h>

// deltaE (CIEDE2000) color loss: mean over 32x512x512 pixels.
// Reference reshapes (B,3,H,W)->(B,H,W,3) WITHOUT transpose => each pixel's
// RGB is 3 consecutive floats. 4 px/thread = 3 float4 loads per image.
//
// Round-5: one 4-px item per thread (8192 blocks), no loop / no prefetch /
// no sched_barrier (round-4 showed the pin + launch-bounds hurt: occ 55->37,
// busy 75->64, dur flat). Zero trig calls: dHp/T/hbar via vector identities;
// the 275-degree Gaussian angle via chord + asin series; sin(2*dtheta) by
// odd poly. Remaining trans: log/exp (sRGB, cbrt), sqrt/rcp/rsq, one exp2.

__device__ __forceinline__ float fexp2(float x) { return __builtin_amdgcn_exp2f(x); }
__device__ __forceinline__ float flog2(float x) { return __builtin_amdgcn_logf(x); }
__device__ __forceinline__ float frcp(float x)  { return __builtin_amdgcn_rcpf(x); }
__device__ __forceinline__ float fsqrt_(float x){ return __builtin_amdgcn_sqrtf(x); }
__device__ __forceinline__ float frsq(float x)  { return __builtin_amdgcn_rsqf(x); }

__device__ __forceinline__ float pow7f(float x) {
    float x2 = x * x;
    float x3 = x2 * x;
    return x3 * x3 * x;
}

__device__ __forceinline__ float srgb_lin(float v) {
    float p = fexp2(2.4f * flog2((v + 0.055f) * (1.0f / 1.055f)));
    return (v <= 0.04045f) ? v * (1.0f / 12.92f) : p;
}

__device__ __forceinline__ float fxyz(float t) {
    float c = fexp2(0.3333333333333333f * flog2(t));
    return (t > 0.008856f) ? c : fmaf(7.787f, t, 16.0f / 116.0f);
}

__device__ __forceinline__ void rgb2lab(float r, float g, float b,
                                        float& L, float& A, float& B) {
    float rl = srgb_lin(r), gl = srgb_lin(g), bl = srgb_lin(b);
    // white point folded into matrix rows (x/0.95047, z/1.08883)
    float x = fmaf(0.43395296f, rl, fmaf(0.37621626f, gl, 0.18982646f * bl));
    float y = fmaf(0.212671f,  rl, fmaf(0.715160f,  gl, 0.072169f  * bl));
    float z = fmaf(0.017757f,  rl, fmaf(0.10946953f, gl, 0.87271810f * bl));
    float fx = fxyz(x), fy = fxyz(y), fz = fxyz(z);
    L = fmaf(116.0f, fy, -16.0f);
    A = 500.0f * (fx - fy);
    B = 200.0f * (fy - fz);
}

__device__ __forceinline__ float ciede2000(float L1, float a1, float b1,
                                           float L2, float a2, float b2) {
    const float P25_7 = 6103515625.0f;        // 25^7

    float b1sq = b1 * b1, b2sq = b2 * b2;
    float C1 = fsqrt_(fmaf(a1, a1, b1sq));
    float C2 = fsqrt_(fmaf(a2, a2, b2sq));
    float Cbar = 0.5f * (C1 + C2);
    float c7 = pow7f(Cbar);
    float G1 = 1.5f - 0.5f * fsqrt_(c7 * frcp(c7 + P25_7));   // 1+G
    float a1p = a1 * G1;
    float a2p = a2 * G1;
    float C1p = fsqrt_(fmaf(a1p, a1p, b1sq));
    float C2p = fsqrt_(fmaf(a2p, a2p, b2sq));
    float CC  = C1p * C2p;

    // dHp = 2*sqrt(CC)*sin(dh/2) = sign(cross) * sqrt(2*(CC - dot))
    float dot   = fmaf(a1p, a2p, b1 * b2);
    float cross = fmaf(b2, a1p, -a2p * b1);
    float dHp = copysignf(fsqrt_(fmaxf(2.0f * (CC - dot), 0.0f)), cross);

    float dLp = L2 - L1;
    float dCp = C2p - C1p;

    // hbar bisector direction = normalize(u1*C2p + u2*C1p); matches the
    // reference's 3-branch hbar for every CC!=0 case (CC==0 is a no-op:
    // dHp=0 => tH=0 kills all hbar-dependent terms).
    float sx = fmaf(a1p, C2p, a2p * C1p);
    float sy = fmaf(b1,  C2p, b2  * C1p);
    float n2 = fmaf(sx, sx, sy * sy);
    float inv = (n2 > 0.0f) ? frsq(n2) : 0.0f;
    float ch = sx * inv, sh = sy * inv;          // cos(hbar), sin(hbar)

    // T by angle addition — no trig
    float c2 = fmaf(2.0f * ch, ch, -1.0f);
    float s2 = 2.0f * sh * ch;
    float c3 = fmaf(c2, ch, -s2 * sh);
    float s3 = fmaf(s2, ch,  c2 * sh);
    float c4 = fmaf(2.0f * c2, c2, -1.0f);
    float s4 = 2.0f * s2 * c2;
    float T = 1.0f
            - 0.17f * fmaf(ch, 0.8660254037844387f, sh * 0.5f)             // cos(h-30)
            + 0.24f * c2
            + 0.32f * fmaf(c3, 0.9945218953682733f, -s3 * 0.10452846326765347f)  // cos(3h+6)
            - 0.20f * fmaf(c4, 0.45399049973954675f, s4 * 0.8910065241883679f);  // cos(4h-63)

    // |hbar - 275deg| via chord + asin series (no atan2). Beyond +-75deg the
    // Gaussian is < 1.2e-4 and series error is irrelevant.
    const float C275 = 0.08715574f;   // cos(275deg)
    const float S275 = -0.9961947f;   // sin(275deg)
    float cphi = fmaf(ch, C275, sh * S275);          // cos(hbar - 275deg)
    float u2 = fmaf(-0.5f, cphi, 0.5f);              // sin^2(phi/2)
    float u  = fsqrt_(fmaxf(u2, 0.0f));
    float halfphi = u * fmaf(u2, fmaf(u2, fmaf(u2, 0.044642857f, 0.075f),
                                      0.16666667f), 1.0f);   // asin(u)
    float td = halfphi * 4.5836624f;                 // 2*phi*(180/pi)/25
    float dtheta = 30.0f * fexp2(-1.4426950408889634f * td * td);

    float Lbar  = 0.5f * (L1 + L2);
    float Cbarp = 0.5f * (C1p + C2p);
    float Lm50 = Lbar - 50.0f;
    float q = Lm50 * Lm50;
    float Sl = fmaf(0.015f * q, frsq(20.0f + q), 1.0f);
    float Sc = fmaf(0.045f, Cbarp, 1.0f);
    float Sh = fmaf(0.015f * Cbarp, T, 1.0f);

    float cb7 = pow7f(Cbarp);
    float Rc = 2.0f * fsqrt_(cb7 * frcp(cb7 + P25_7));
    // sin(2*dtheta deg): arg = dtheta*pi/90 <= 1.047 rad; odd poly deg-5
    float xr = dtheta * 0.034906585f;
    float xr2 = xr * xr;
    float sin2dt = xr * fmaf(xr2, fmaf(xr2, 8.3333338e-3f, -1.6666667e-1f), 1.0f);
    float Rt = -Rc * sin2dt;

    float ScSh = Sc * Sh;
    float R3 = frcp(Sl * ScSh);
    float tL = dLp * ScSh * R3;
    float tC = dCp * (Sl * Sh) * R3;
    float tH = dHp * (Sl * Sc) * R3;
    float s = fmaf(tL, tL, fmaf(tC, tC, fmaf(tH, tH, Rt * tC * tH)));
    return fsqrt_(fmaxf(s, 0.0f));
}

__device__ __forceinline__ float de_px(float gr, float gg, float gb,
                                       float rr, float rg, float rb) {
    float L1, A1, B1, L2, A2, B2;
    rgb2lab(rr, rg, rb, L1, A1, B1);   // gt
    rgb2lab(gr, gg, gb, L2, A2, B2);   // gen
    return fabsf(ciede2000(L1, A1, B1, L2, A2, B2));
}

// 4 pixels from 3 float4s each, named components (no arrays -> no scratch).
__device__ __forceinline__ float process4(const float4& g0, const float4& g1,
                                          const float4& g2, const float4& r0,
                                          const float4& r1, const float4& r2) {
    float acc;
    acc  = de_px(g0.x, g0.y, g0.z, r0.x, r0.y, r0.z);
    acc += de_px(g0.w, g1.x, g1.y, r0.w, r1.x, r1.y);
    acc += de_px(g1.z, g1.w, g2.x, r1.z, r1.w, r2.x);
    acc += de_px(g2.y, g2.z, g2.w, r2.y, r2.z, r2.w);
    return acc;
}

__device__ __forceinline__ void block_reduce_store(float acc, float* dst) {
    for (int off = 32; off > 0; off >>= 1) acc += __shfl_down(acc, off, 64);
    __shared__ float sm[4];
    int lane = threadIdx.x & 63;
    int wid  = threadIdx.x >> 6;
    if (lane == 0) sm[wid] = acc;
    __syncthreads();
    if (threadIdx.x == 0) *dst = sm[0] + sm[1] + sm[2] + sm[3];
}

// One 4-pixel item per thread: max TLP, loads issue at wave birth.
__global__ __launch_bounds__(256) void de_main1(const float4* __restrict__ gen,
                                                const float4* __restrict__ gt,
                                                float* __restrict__ partial) {
    int t = blockIdx.x * 256 + threadIdx.x;
    float4 g0 = gen[3 * t + 0], g1 = gen[3 * t + 1], g2 = gen[3 * t + 2];
    float4 r0 = gt [3 * t + 0], r1 = gt [3 * t + 1], r2 = gt [3 * t + 2];
    float acc = process4(g0, g1, g2, r0, r1, r2);
    block_reduce_store(acc, &partial[blockIdx.x]);
}

// Generic fallback (bounds-checked grid-stride), used only if sizes change.
__global__ __launch_bounds__(256) void de_main_gen(const float4* __restrict__ gen,
                                                   const float4* __restrict__ gt,
                                                   float* __restrict__ partial,
                                                   int ntrip) {
    int tid = blockIdx.x * blockDim.x + threadIdx.x;
    int stride = gridDim.x * blockDim.x;
    float acc = 0.0f;
    for (int t = tid; t < ntrip; t += stride) {
        float4 g0 = gen[3 * t + 0], g1 = gen[3 * t + 1], g2 = gen[3 * t + 2];
        float4 r0 = gt [3 * t + 0], r1 = gt [3 * t + 1], r2 = gt [3 * t + 2];
        acc += process4(g0, g1, g2, r0, r1, r2);
    }
    block_reduce_store(acc, &partial[blockIdx.x]);
}

__global__ __launch_bounds__(256) void de_final(const float* __restrict__ partial,
                                                float* __restrict__ out,
                                                int n, float inv_npix) {
    float acc = 0.0f;
    for (int i = threadIdx.x; i < n; i += 256) acc += partial[i];
    for (int off = 32; off > 0; off >>= 1) acc += __shfl_down(acc, off, 64);
    __shared__ float sm[4];
    int lane = threadIdx.x & 63;
    int wid  = threadIdx.x >> 6;
    if (lane == 0) sm[wid] = acc;
    __syncthreads();
    if (threadIdx.x == 0) out[0] = (sm[0] + sm[1] + sm[2] + sm[3]) * inv_npix;
}

extern "C" void kernel_launch(void* const* d_in, const int* in_sizes, int n_in,
                              void* d_out, int out_size, void* d_ws, size_t ws_size,
                              hipStream_t stream) {
    const float4* gen = (const float4*)d_in[0];  // genImage
    const float4* gt  = (const float4*)d_in[1];  // gtImage

    const int total_f = in_sizes[0];             // 25,165,824 floats
    const int ntrip   = total_f / 12;            // 4-pixel work items
    const int npix    = total_f / 3;

    float* partial = (float*)d_ws;

    if (ntrip == 8192 * 256) {
        de_main1<<<8192, 256, 0, stream>>>(gen, gt, partial);
        de_final<<<1, 256, 0, stream>>>(partial, (float*)d_out,
                                        8192, 1.0f / (float)npix);
    } else {
        const int blocks = 2048;
        de_main_gen<<<blocks, 256, 0, stream>>>(gen, gt, partial, ntrip);
        de_final<<<1, 256, 0, stream>>>(partial, (float*)d_out,
                                        blocks, 1.0f / (float)npix);
    }
}

// Round 7
// 74.293 us; speedup vs baseline: 1.0397x; 1.0397x over previous
//
#include <hip/hip_runtime.h>

// deltaE (CIEDE2000) color loss: mean over 32x512x512 pixels.
// Reference reshapes (B,3,H,W)->(B,H,W,3) WITHOUT transpose => each pixel's
// RGB is 3 consecutive floats. 4 px/thread = 3 float4 loads per image.
//
// Round-7 (= round-6 fixed): two pixels in LOCKSTEP through the pipeline via
// an explicit 2-wide struct (F2). Rounds 3-5 compiled to VGPR 24-44 with the
// register-minimizing allocator serializing per-pixel dependency chains
// (VALUBusy stuck ~72-75%). Pairwise code halves chain depth per result.
// Gaussian via asin^2 series in u^2 (no sqrt, no atan2, no trig anywhere).

__device__ __forceinline__ float fexp2(float x) { return __builtin_amdgcn_exp2f(x); }
__device__ __forceinline__ float flog2(float x) { return __builtin_amdgcn_logf(x); }
__device__ __forceinline__ float frcp(float x)  { return __builtin_amdgcn_rcpf(x); }
__device__ __forceinline__ float fsqrt_(float x){ return __builtin_amdgcn_sqrtf(x); }
__device__ __forceinline__ float frsq(float x)  { return __builtin_amdgcn_rsqf(x); }

// ---- 2-wide float: every op written pairwise, full operator set ------------
struct F2 { float a, b; };
__device__ __forceinline__ F2 mkF2(float a, float b) { return {a, b}; }
__device__ __forceinline__ F2 operator+(F2 x, F2 y) { return {x.a + y.a, x.b + y.b}; }
__device__ __forceinline__ F2 operator-(F2 x, F2 y) { return {x.a - y.a, x.b - y.b}; }
__device__ __forceinline__ F2 operator*(F2 x, F2 y) { return {x.a * y.a, x.b * y.b}; }
__device__ __forceinline__ F2 operator*(float s, F2 x) { return {s * x.a, s * x.b}; }
__device__ __forceinline__ F2 operator*(F2 x, float s) { return {x.a * s, x.b * s}; }
__device__ __forceinline__ F2 operator+(F2 x, float s) { return {x.a + s, x.b + s}; }
__device__ __forceinline__ F2 operator+(float s, F2 x) { return {s + x.a, s + x.b}; }
__device__ __forceinline__ F2 operator-(float s, F2 x) { return {s - x.a, s - x.b}; }
__device__ __forceinline__ F2 operator-(F2 x, float s) { return {x.a - s, x.b - s}; }
__device__ __forceinline__ F2 operator-(F2 x) { return {-x.a, -x.b}; }
__device__ __forceinline__ F2 f2fma(F2 x, F2 y, F2 z) {
    return {fmaf(x.a, y.a, z.a), fmaf(x.b, y.b, z.b)};
}
__device__ __forceinline__ F2 f2fma(F2 x, float y, F2 z) {
    return {fmaf(x.a, y, z.a), fmaf(x.b, y, z.b)};
}
__device__ __forceinline__ F2 f2fma(float x, F2 y, F2 z) {
    return {fmaf(x, y.a, z.a), fmaf(x, y.b, z.b)};
}
__device__ __forceinline__ F2 f2sqrt(F2 x) { return {fsqrt_(x.a), fsqrt_(x.b)}; }
__device__ __forceinline__ F2 f2rcp(F2 x)  { return {frcp(x.a), frcp(x.b)}; }
__device__ __forceinline__ F2 f2rsq(F2 x)  { return {frsq(x.a), frsq(x.b)}; }
__device__ __forceinline__ F2 f2exp2(F2 x) { return {fexp2(x.a), fexp2(x.b)}; }
__device__ __forceinline__ F2 f2log2(F2 x) { return {flog2(x.a), flog2(x.b)}; }
__device__ __forceinline__ F2 f2max(F2 x, float s) { return {fmaxf(x.a, s), fmaxf(x.b, s)}; }
__device__ __forceinline__ F2 f2abs(F2 x)  { return {fabsf(x.a), fabsf(x.b)}; }
__device__ __forceinline__ F2 f2copysign(F2 x, F2 s) {
    return {copysignf(x.a, s.a), copysignf(x.b, s.b)};
}

__device__ __forceinline__ F2 f2pow7(F2 x) {
    F2 x2 = x * x;
    F2 x3 = x2 * x;
    return x3 * x3 * x;
}

__device__ __forceinline__ F2 f2srgb(F2 v) {
    F2 p = f2exp2(2.4f * f2log2((v + 0.055f) * (1.0f / 1.055f)));
    return {(v.a <= 0.04045f) ? v.a * (1.0f / 12.92f) : p.a,
            (v.b <= 0.04045f) ? v.b * (1.0f / 12.92f) : p.b};
}

__device__ __forceinline__ F2 f2fxyz(F2 t) {
    F2 c = f2exp2(0.3333333333333333f * f2log2(t));
    return {(t.a > 0.008856f) ? c.a : fmaf(7.787f, t.a, 16.0f / 116.0f),
            (t.b > 0.008856f) ? c.b : fmaf(7.787f, t.b, 16.0f / 116.0f)};
}

__device__ __forceinline__ void rgb2lab2(F2 r, F2 g, F2 b,
                                         F2& L, F2& A, F2& B) {
    F2 rl = f2srgb(r), gl = f2srgb(g), bl = f2srgb(b);
    // white point folded into matrix rows (x/0.95047, z/1.08883)
    F2 x = f2fma(0.43395296f, rl, f2fma(0.37621626f, gl, 0.18982646f * bl));
    F2 y = f2fma(0.212671f,  rl, f2fma(0.715160f,  gl, 0.072169f  * bl));
    F2 z = f2fma(0.017757f,  rl, f2fma(0.10946953f, gl, 0.87271810f * bl));
    F2 fx = f2fxyz(x), fy = f2fxyz(y), fz = f2fxyz(z);
    L = f2fma(116.0f, fy, mkF2(-16.0f, -16.0f));
    A = 500.0f * (fx - fy);
    B = 200.0f * (fy - fz);
}

// CIEDE2000 for two pixel-pairs in lockstep; returns dE.a + dE.b
__device__ __forceinline__ float ciede2(F2 L1, F2 a1, F2 b1,
                                        F2 L2, F2 a2, F2 b2) {
    const float P25_7 = 6103515625.0f;        // 25^7

    F2 b1sq = b1 * b1, b2sq = b2 * b2;
    F2 C1 = f2sqrt(f2fma(a1, a1, b1sq));
    F2 C2 = f2sqrt(f2fma(a2, a2, b2sq));
    F2 Cbar = 0.5f * (C1 + C2);
    F2 c7 = f2pow7(Cbar);
    F2 G1 = 1.5f - 0.5f * f2sqrt(c7 * f2rcp(c7 + P25_7));   // 1+G
    F2 a1p = a1 * G1;
    F2 a2p = a2 * G1;
    F2 C1p = f2sqrt(f2fma(a1p, a1p, b1sq));
    F2 C2p = f2sqrt(f2fma(a2p, a2p, b2sq));
    F2 CC  = C1p * C2p;

    // dHp = sign(cross)*sqrt(2*(CC - dot)); dot/cross from vector identity
    F2 dot   = f2fma(a1p, a2p, b1 * b2);
    F2 cross = f2fma(b2, a1p, -(a2p * b1));
    F2 dHp = f2copysign(f2sqrt(f2max(2.0f * (CC - dot), 0.0f)), cross);

    F2 dLp = L2 - L1;
    F2 dCp = C2p - C1p;

    // hbar bisector = normalize(u1*C2p + u2*C1p); CC==0 cases are no-ops
    // (dHp=0 => tH=0 kills all hbar-dependent terms).
    F2 sx = f2fma(a1p, C2p, a2p * C1p);
    F2 sy = f2fma(b1,  C2p, b2  * C1p);
    F2 n2 = f2fma(sx, sx, sy * sy);
    F2 inv = {(n2.a > 0.0f) ? frsq(n2.a) : 0.0f,
              (n2.b > 0.0f) ? frsq(n2.b) : 0.0f};
    F2 ch = sx * inv, sh = sy * inv;          // cos(hbar), sin(hbar)

    // T by angle addition — no trig
    F2 c2v = f2fma(2.0f * ch, ch, mkF2(-1.0f, -1.0f));
    F2 s2v = 2.0f * sh * ch;
    F2 c3v = f2fma(c2v, ch, -(s2v * sh));
    F2 s3v = f2fma(s2v, ch, c2v * sh);
    F2 c4v = f2fma(2.0f * c2v, c2v, mkF2(-1.0f, -1.0f));
    F2 s4v = 2.0f * s2v * c2v;
    F2 T = 1.0f - 0.17f * f2fma(ch, 0.8660254037844387f, sh * 0.5f)
         + 0.24f * c2v
         + 0.32f * f2fma(c3v, 0.9945218953682733f, s3v * (-0.10452846326765347f))
         - 0.20f * f2fma(c4v, 0.45399049973954675f, s4v * 0.8910065241883679f);

    // Gaussian angle: td^2 = (phi_deg/25)^2 via asin^2 series in u2 (no sqrt)
    // u2 = sin^2(phi/2); asin^2(u)/u^2 = 1 + u2/3 + 8u2^2/45 + 4u2^3/35
    const float C275 = 0.08715574f, S275 = -0.9961947f;
    F2 cphi = f2fma(ch, C275, sh * S275);          // cos(hbar - 275deg)
    F2 u2 = f2max(f2fma(cphi, -0.5f, mkF2(0.5f, 0.5f)), 0.0f);
    F2 ser = f2fma(u2, f2fma(u2, f2fma(u2, mkF2(0.11428571f, 0.11428571f),
                                       mkF2(0.17777778f, 0.17777778f)),
                             mkF2(0.33333333f, 0.33333333f)),
                   mkF2(1.0f, 1.0f));
    F2 td2 = 21.00996f * (u2 * ser);               // (4.5836624^2)*asin^2(u)
    F2 dtheta = 30.0f * f2exp2(-1.4426950408889634f * td2);

    F2 Lbar  = 0.5f * (L1 + L2);
    F2 Cbarp = 0.5f * (C1p + C2p);
    F2 Lm50 = Lbar - 50.0f;
    F2 q = Lm50 * Lm50;
    F2 Sl = f2fma(0.015f * q, f2rsq(q + 20.0f), mkF2(1.0f, 1.0f));
    F2 Sc = f2fma(0.045f, Cbarp, mkF2(1.0f, 1.0f));
    F2 Sh = f2fma(0.015f * Cbarp, T, mkF2(1.0f, 1.0f));

    F2 cb7 = f2pow7(Cbarp);
    F2 Rc = 2.0f * f2sqrt(cb7 * f2rcp(cb7 + P25_7));
    // sin(2*dtheta deg): arg <= 1.047 rad; odd poly deg-5
    F2 xr = 0.034906585f * dtheta;
    F2 xr2 = xr * xr;
    F2 sin2dt = xr * f2fma(xr2, f2fma(xr2, mkF2(8.3333338e-3f, 8.3333338e-3f),
                                      mkF2(-1.6666667e-1f, -1.6666667e-1f)),
                           mkF2(1.0f, 1.0f));
    F2 Rt = -(Rc * sin2dt);

    F2 ScSh = Sc * Sh;
    F2 R3 = f2rcp(Sl * ScSh);
    F2 tL = dLp * ScSh * R3;
    F2 tC = dCp * (Sl * Sh) * R3;
    F2 tH = dHp * (Sl * Sc) * R3;
    F2 s = f2fma(tL, tL, f2fma(tC, tC, f2fma(tH, tH, Rt * tC * tH)));
    F2 dE = f2sqrt(f2max(s, 0.0f));
    return fabsf(dE.a) + fabsf(dE.b);
}

// two pixel-pairs -> sum of their dE
__device__ __forceinline__ float de2(F2 gr, F2 gg, F2 gb,
                                     F2 rr, F2 rg, F2 rb) {
    F2 L1, A1, B1, L2, A2, B2;
    rgb2lab2(rr, rg, rb, L1, A1, B1);   // gt
    rgb2lab2(gr, gg, gb, L2, A2, B2);   // gen
    return ciede2(L1, A1, B1, L2, A2, B2);
}

// 4 pixels from 3 float4s per image: two lockstep pairs.
__device__ __forceinline__ float process4(const float4& g0, const float4& g1,
                                          const float4& g2, const float4& r0,
                                          const float4& r1, const float4& r2) {
    float acc;
    acc  = de2(mkF2(g0.x, g0.w), mkF2(g0.y, g1.x), mkF2(g0.z, g1.y),
               mkF2(r0.x, r0.w), mkF2(r0.y, r1.x), mkF2(r0.z, r1.y));
    acc += de2(mkF2(g1.z, g2.y), mkF2(g1.w, g2.z), mkF2(g2.x, g2.w),
               mkF2(r1.z, r2.y), mkF2(r1.w, r2.z), mkF2(r2.x, r2.w));
    return acc;
}

__device__ __forceinline__ void block_reduce_store(float acc, float* dst) {
    for (int off = 32; off > 0; off >>= 1) acc += __shfl_down(acc, off, 64);
    __shared__ float sm[4];
    int lane = threadIdx.x & 63;
    int wid  = threadIdx.x >> 6;
    if (lane == 0) sm[wid] = acc;
    __syncthreads();
    if (threadIdx.x == 0) *dst = sm[0] + sm[1] + sm[2] + sm[3];
}

// One 4-pixel item per thread.
__global__ __launch_bounds__(256) void de_main1(const float4* __restrict__ gen,
                                                const float4* __restrict__ gt,
                                                float* __restrict__ partial) {
    int t = blockIdx.x * 256 + threadIdx.x;
    float4 g0 = gen[3 * t + 0], g1 = gen[3 * t + 1], g2 = gen[3 * t + 2];
    float4 r0 = gt [3 * t + 0], r1 = gt [3 * t + 1], r2 = gt [3 * t + 2];
    float acc = process4(g0, g1, g2, r0, r1, r2);
    block_reduce_store(acc, &partial[blockIdx.x]);
}

// Generic fallback (bounds-checked grid-stride), used only if sizes change.
__global__ __launch_bounds__(256) void de_main_gen(const float4* __restrict__ gen,
                                                   const float4* __restrict__ gt,
                                                   float* __restrict__ partial,
                                                   int ntrip) {
    int tid = blockIdx.x * blockDim.x + threadIdx.x;
    int stride = gridDim.x * blockDim.x;
    float acc = 0.0f;
    for (int t = tid; t < ntrip; t += stride) {
        float4 g0 = gen[3 * t + 0], g1 = gen[3 * t + 1], g2 = gen[3 * t + 2];
        float4 r0 = gt [3 * t + 0], r1 = gt [3 * t + 1], r2 = gt [3 * t + 2];
        acc += process4(g0, g1, g2, r0, r1, r2);
    }
    block_reduce_store(acc, &partial[blockIdx.x]);
}

__global__ __launch_bounds__(256) void de_final(const float* __restrict__ partial,
                                                float* __restrict__ out,
                                                int n, float inv_npix) {
    float acc = 0.0f;
    for (int i = threadIdx.x; i < n; i += 256) acc += partial[i];
    for (int off = 32; off > 0; off >>= 1) acc += __shfl_down(acc, off, 64);
    __shared__ float sm[4];
    int lane = threadIdx.x & 63;
    int wid  = threadIdx.x >> 6;
    if (lane == 0) sm[wid] = acc;
    __syncthreads();
    if (threadIdx.x == 0) out[0] = (sm[0] + sm[1] + sm[2] + sm[3]) * inv_npix;
}

extern "C" void kernel_launch(void* const* d_in, const int* in_sizes, int n_in,
                              void* d_out, int out_size, void* d_ws, size_t ws_size,
                              hipStream_t stream) {
    const float4* gen = (const float4*)d_in[0];  // genImage
    const float4* gt  = (const float4*)d_in[1];  // gtImage

    const int total_f = in_sizes[0];             // 25,165,824 floats
    const int ntrip   = total_f / 12;            // 4-pixel work items
    const int npix    = total_f / 3;

    float* partial = (float*)d_ws;

    if (ntrip == 8192 * 256) {
        de_main1<<<8192, 256, 0, stream>>>(gen, gt, partial);
        de_final<<<1, 256, 0, stream>>>(partial, (float*)d_out,
                                        8192, 1.0f / (float)npix);
    } else {
        const int blocks = 2048;
        de_main_gen<<<blocks, 256, 0, stream>>>(gen, gt, partial, ntrip);
        de_final<<<1, 256, 0, stream>>>(partial, (float*)d_out,
                                        blocks, 1.0f / (float)npix);
    }
}

// Round 8
// 66.987 us; speedup vs baseline: 1.1530x; 1.1091x over previous
//
#include <hip/hip_runtime.h>

// deltaE (CIEDE2000) color loss: mean over 32x512x512 pixels.
// Reference reshapes (B,3,H,W)->(B,H,W,3) WITHOUT transpose => each pixel's
// RGB is 3 consecutive floats. 4 px/thread-item = 3 float4 loads per image.
//
// Round-8: same trans-minimal F2 lockstep pipeline as round-7, but compiled
// under amdgpu_waves_per_eu(2,4): the backend scheduler's pressure target
// becomes 128 VGPR (4 waves/EU) instead of max-occupancy, so the paired
// chains + a 1-deep prefetch survive regalloc (r3-r7 all collapsed to
// VGPR 24-44 and serialized; busy stuck ~75%, ~1.5x issue bloat).
// Looped 4-item structure amortizes the wave-startup load stall that the
// no-loop r5/r7 shape paid every 2720 cycles (~25% idle).

__device__ __forceinline__ float fexp2(float x) { return __builtin_amdgcn_exp2f(x); }
__device__ __forceinline__ float flog2(float x) { return __builtin_amdgcn_logf(x); }
__device__ __forceinline__ float frcp(float x)  { return __builtin_amdgcn_rcpf(x); }
__device__ __forceinline__ float fsqrt_(float x){ return __builtin_amdgcn_sqrtf(x); }
__device__ __forceinline__ float frsq(float x)  { return __builtin_amdgcn_rsqf(x); }

// ---- 2-wide float: every op written pairwise, full operator set ------------
struct F2 { float a, b; };
__device__ __forceinline__ F2 mkF2(float a, float b) { return {a, b}; }
__device__ __forceinline__ F2 operator+(F2 x, F2 y) { return {x.a + y.a, x.b + y.b}; }
__device__ __forceinline__ F2 operator-(F2 x, F2 y) { return {x.a - y.a, x.b - y.b}; }
__device__ __forceinline__ F2 operator*(F2 x, F2 y) { return {x.a * y.a, x.b * y.b}; }
__device__ __forceinline__ F2 operator*(float s, F2 x) { return {s * x.a, s * x.b}; }
__device__ __forceinline__ F2 operator*(F2 x, float s) { return {x.a * s, x.b * s}; }
__device__ __forceinline__ F2 operator+(F2 x, float s) { return {x.a + s, x.b + s}; }
__device__ __forceinline__ F2 operator+(float s, F2 x) { return {s + x.a, s + x.b}; }
__device__ __forceinline__ F2 operator-(float s, F2 x) { return {s - x.a, s - x.b}; }
__device__ __forceinline__ F2 operator-(F2 x, float s) { return {x.a - s, x.b - s}; }
__device__ __forceinline__ F2 operator-(F2 x) { return {-x.a, -x.b}; }
__device__ __forceinline__ F2 f2fma(F2 x, F2 y, F2 z) {
    return {fmaf(x.a, y.a, z.a), fmaf(x.b, y.b, z.b)};
}
__device__ __forceinline__ F2 f2fma(F2 x, float y, F2 z) {
    return {fmaf(x.a, y, z.a), fmaf(x.b, y, z.b)};
}
__device__ __forceinline__ F2 f2fma(float x, F2 y, F2 z) {
    return {fmaf(x, y.a, z.a), fmaf(x, y.b, z.b)};
}
__device__ __forceinline__ F2 f2sqrt(F2 x) { return {fsqrt_(x.a), fsqrt_(x.b)}; }
__device__ __forceinline__ F2 f2rcp(F2 x)  { return {frcp(x.a), frcp(x.b)}; }
__device__ __forceinline__ F2 f2rsq(F2 x)  { return {frsq(x.a), frsq(x.b)}; }
__device__ __forceinline__ F2 f2exp2(F2 x) { return {fexp2(x.a), fexp2(x.b)}; }
__device__ __forceinline__ F2 f2log2(F2 x) { return {flog2(x.a), flog2(x.b)}; }
__device__ __forceinline__ F2 f2max(F2 x, float s) { return {fmaxf(x.a, s), fmaxf(x.b, s)}; }
__device__ __forceinline__ F2 f2copysign(F2 x, F2 s) {
    return {copysignf(x.a, s.a), copysignf(x.b, s.b)};
}

__device__ __forceinline__ F2 f2pow7(F2 x) {
    F2 x2 = x * x;
    F2 x3 = x2 * x;
    return x3 * x3 * x;
}

__device__ __forceinline__ F2 f2srgb(F2 v) {
    F2 p = f2exp2(2.4f * f2log2((v + 0.055f) * (1.0f / 1.055f)));
    return {(v.a <= 0.04045f) ? v.a * (1.0f / 12.92f) : p.a,
            (v.b <= 0.04045f) ? v.b * (1.0f / 12.92f) : p.b};
}

__device__ __forceinline__ F2 f2fxyz(F2 t) {
    F2 c = f2exp2(0.3333333333333333f * f2log2(t));
    return {(t.a > 0.008856f) ? c.a : fmaf(7.787f, t.a, 16.0f / 116.0f),
            (t.b > 0.008856f) ? c.b : fmaf(7.787f, t.b, 16.0f / 116.0f)};
}

__device__ __forceinline__ void rgb2lab2(F2 r, F2 g, F2 b,
                                         F2& L, F2& A, F2& B) {
    F2 rl = f2srgb(r), gl = f2srgb(g), bl = f2srgb(b);
    // white point folded into matrix rows (x/0.95047, z/1.08883)
    F2 x = f2fma(0.43395296f, rl, f2fma(0.37621626f, gl, 0.18982646f * bl));
    F2 y = f2fma(0.212671f,  rl, f2fma(0.715160f,  gl, 0.072169f  * bl));
    F2 z = f2fma(0.017757f,  rl, f2fma(0.10946953f, gl, 0.87271810f * bl));
    F2 fx = f2fxyz(x), fy = f2fxyz(y), fz = f2fxyz(z);
    L = f2fma(116.0f, fy, mkF2(-16.0f, -16.0f));
    A = 500.0f * (fx - fy);
    B = 200.0f * (fy - fz);
}

// CIEDE2000 for two pixel-pairs in lockstep; returns dE.a + dE.b
__device__ __forceinline__ float ciede2(F2 L1, F2 a1, F2 b1,
                                        F2 L2, F2 a2, F2 b2) {
    const float P25_7 = 6103515625.0f;        // 25^7

    F2 b1sq = b1 * b1, b2sq = b2 * b2;
    F2 C1 = f2sqrt(f2fma(a1, a1, b1sq));
    F2 C2 = f2sqrt(f2fma(a2, a2, b2sq));
    F2 Cbar = 0.5f * (C1 + C2);
    F2 c7 = f2pow7(Cbar);
    F2 G1 = 1.5f - 0.5f * f2sqrt(c7 * f2rcp(c7 + P25_7));   // 1+G
    F2 a1p = a1 * G1;
    F2 a2p = a2 * G1;
    F2 C1p = f2sqrt(f2fma(a1p, a1p, b1sq));
    F2 C2p = f2sqrt(f2fma(a2p, a2p, b2sq));
    F2 CC  = C1p * C2p;

    // dHp = sign(cross)*sqrt(2*(CC - dot)); dot/cross from vector identity
    F2 dot   = f2fma(a1p, a2p, b1 * b2);
    F2 cross = f2fma(b2, a1p, -(a2p * b1));
    F2 dHp = f2copysign(f2sqrt(f2max(2.0f * (CC - dot), 0.0f)), cross);

    F2 dLp = L2 - L1;
    F2 dCp = C2p - C1p;

    // hbar bisector = normalize(u1*C2p + u2*C1p); CC==0 cases are no-ops
    // (dHp=0 => tH=0 kills all hbar-dependent terms).
    F2 sx = f2fma(a1p, C2p, a2p * C1p);
    F2 sy = f2fma(b1,  C2p, b2  * C1p);
    F2 n2 = f2fma(sx, sx, sy * sy);
    F2 inv = {(n2.a > 0.0f) ? frsq(n2.a) : 0.0f,
              (n2.b > 0.0f) ? frsq(n2.b) : 0.0f};
    F2 ch = sx * inv, sh = sy * inv;          // cos(hbar), sin(hbar)

    // T by angle addition — no trig
    F2 c2v = f2fma(2.0f * ch, ch, mkF2(-1.0f, -1.0f));
    F2 s2v = 2.0f * sh * ch;
    F2 c3v = f2fma(c2v, ch, -(s2v * sh));
    F2 s3v = f2fma(s2v, ch, c2v * sh);
    F2 c4v = f2fma(2.0f * c2v, c2v, mkF2(-1.0f, -1.0f));
    F2 s4v = 2.0f * s2v * c2v;
    F2 T = 1.0f - 0.17f * f2fma(ch, 0.8660254037844387f, sh * 0.5f)
         + 0.24f * c2v
         + 0.32f * f2fma(c3v, 0.9945218953682733f, s3v * (-0.10452846326765347f))
         - 0.20f * f2fma(c4v, 0.45399049973954675f, s4v * 0.8910065241883679f);

    // Gaussian angle: td^2 = (phi_deg/25)^2 via asin^2 series in u2 (no sqrt)
    // u2 = sin^2(phi/2); asin^2(u)/u^2 = 1 + u2/3 + 8u2^2/45 + 4u2^3/35
    const float C275 = 0.08715574f, S275 = -0.9961947f;
    F2 cphi = f2fma(ch, C275, sh * S275);          // cos(hbar - 275deg)
    F2 u2 = f2max(f2fma(cphi, -0.5f, mkF2(0.5f, 0.5f)), 0.0f);
    F2 ser = f2fma(u2, f2fma(u2, f2fma(u2, mkF2(0.11428571f, 0.11428571f),
                                       mkF2(0.17777778f, 0.17777778f)),
                             mkF2(0.33333333f, 0.33333333f)),
                   mkF2(1.0f, 1.0f));
    F2 td2 = 21.00996f * (u2 * ser);               // (4.5836624^2)*asin^2(u)
    F2 dtheta = 30.0f * f2exp2(-1.4426950408889634f * td2);

    F2 Lbar  = 0.5f * (L1 + L2);
    F2 Cbarp = 0.5f * (C1p + C2p);
    F2 Lm50 = Lbar - 50.0f;
    F2 q = Lm50 * Lm50;
    F2 Sl = f2fma(0.015f * q, f2rsq(q + 20.0f), mkF2(1.0f, 1.0f));
    F2 Sc = f2fma(0.045f, Cbarp, mkF2(1.0f, 1.0f));
    F2 Sh = f2fma(0.015f * Cbarp, T, mkF2(1.0f, 1.0f));

    F2 cb7 = f2pow7(Cbarp);
    F2 Rc = 2.0f * f2sqrt(cb7 * f2rcp(cb7 + P25_7));
    // sin(2*dtheta deg): arg <= 1.047 rad; odd poly deg-5
    F2 xr = 0.034906585f * dtheta;
    F2 xr2 = xr * xr;
    F2 sin2dt = xr * f2fma(xr2, f2fma(xr2, mkF2(8.3333338e-3f, 8.3333338e-3f),
                                      mkF2(-1.6666667e-1f, -1.6666667e-1f)),
                           mkF2(1.0f, 1.0f));
    F2 Rt = -(Rc * sin2dt);

    F2 ScSh = Sc * Sh;
    F2 R3 = f2rcp(Sl * ScSh);
    F2 tL = dLp * ScSh * R3;
    F2 tC = dCp * (Sl * Sh) * R3;
    F2 tH = dHp * (Sl * Sc) * R3;
    F2 s = f2fma(tL, tL, f2fma(tC, tC, f2fma(tH, tH, Rt * tC * tH)));
    F2 dE = f2sqrt(f2max(s, 0.0f));
    return fabsf(dE.a) + fabsf(dE.b);
}

// two pixel-pairs -> sum of their dE
__device__ __forceinline__ float de2(F2 gr, F2 gg, F2 gb,
                                     F2 rr, F2 rg, F2 rb) {
    F2 L1, A1, B1, L2, A2, B2;
    rgb2lab2(rr, rg, rb, L1, A1, B1);   // gt
    rgb2lab2(gr, gg, gb, L2, A2, B2);   // gen
    return ciede2(L1, A1, B1, L2, A2, B2);
}

// 4 pixels from 3 float4s per image: two lockstep pairs.
__device__ __forceinline__ float process4(const float4& g0, const float4& g1,
                                          const float4& g2, const float4& r0,
                                          const float4& r1, const float4& r2) {
    float acc;
    acc  = de2(mkF2(g0.x, g0.w), mkF2(g0.y, g1.x), mkF2(g0.z, g1.y),
               mkF2(r0.x, r0.w), mkF2(r0.y, r1.x), mkF2(r0.z, r1.y));
    acc += de2(mkF2(g1.z, g2.y), mkF2(g1.w, g2.z), mkF2(g2.x, g2.w),
               mkF2(r1.z, r2.y), mkF2(r1.w, r2.z), mkF2(r2.x, r2.w));
    return acc;
}

__device__ __forceinline__ void block_reduce_store(float acc, float* dst) {
    for (int off = 32; off > 0; off >>= 1) acc += __shfl_down(acc, off, 64);
    __shared__ float sm[4];
    int lane = threadIdx.x & 63;
    int wid  = threadIdx.x >> 6;
    if (lane == 0) sm[wid] = acc;
    __syncthreads();
    if (threadIdx.x == 0) *dst = sm[0] + sm[1] + sm[2] + sm[3];
}

// Exact-trip looped kernel, 1-deep register prefetch, ILP-friendly pressure
// target via amdgpu_waves_per_eu(2,4): allocator may use up to 256 VGPR,
// scheduler stops pressure-reduction at 128 (4 waves/EU).
template <int NITER>
__global__ __attribute__((amdgpu_waves_per_eu(2, 4)))
__launch_bounds__(256) void de_main_fix(const float4* __restrict__ gen,
                                        const float4* __restrict__ gt,
                                        float* __restrict__ partial,
                                        int stride) {
    int t = blockIdx.x * 256 + threadIdx.x;
    float acc = 0.0f;

    float4 cg0 = gen[3 * t + 0], cg1 = gen[3 * t + 1], cg2 = gen[3 * t + 2];
    float4 cr0 = gt [3 * t + 0], cr1 = gt [3 * t + 1], cr2 = gt [3 * t + 2];

    #pragma unroll 1
    for (int it = 0; it < NITER - 1; ++it) {
        int tn = t + stride;
        float4 ng0 = gen[3 * tn + 0], ng1 = gen[3 * tn + 1], ng2 = gen[3 * tn + 2];
        float4 nr0 = gt [3 * tn + 0], nr1 = gt [3 * tn + 1], nr2 = gt [3 * tn + 2];
        acc += process4(cg0, cg1, cg2, cr0, cr1, cr2);
        cg0 = ng0; cg1 = ng1; cg2 = ng2;
        cr0 = nr0; cr1 = nr1; cr2 = nr2;
        t = tn;
    }
    acc += process4(cg0, cg1, cg2, cr0, cr1, cr2);

    block_reduce_store(acc, &partial[blockIdx.x]);
}

// Generic fallback (bounds-checked grid-stride), used only if sizes change.
__global__ __launch_bounds__(256) void de_main_gen(const float4* __restrict__ gen,
                                                   const float4* __restrict__ gt,
                                                   float* __restrict__ partial,
                                                   int ntrip) {
    int tid = blockIdx.x * blockDim.x + threadIdx.x;
    int stride = gridDim.x * blockDim.x;
    float acc = 0.0f;
    for (int t = tid; t < ntrip; t += stride) {
        float4 g0 = gen[3 * t + 0], g1 = gen[3 * t + 1], g2 = gen[3 * t + 2];
        float4 r0 = gt [3 * t + 0], r1 = gt [3 * t + 1], r2 = gt [3 * t + 2];
        acc += process4(g0, g1, g2, r0, r1, r2);
    }
    block_reduce_store(acc, &partial[blockIdx.x]);
}

__global__ __launch_bounds__(256) void de_final(const float* __restrict__ partial,
                                                float* __restrict__ out,
                                                int n, float inv_npix) {
    float acc = 0.0f;
    for (int i = threadIdx.x; i < n; i += 256) acc += partial[i];
    for (int off = 32; off > 0; off >>= 1) acc += __shfl_down(acc, off, 64);
    __shared__ float sm[4];
    int lane = threadIdx.x & 63;
    int wid  = threadIdx.x >> 6;
    if (lane == 0) sm[wid] = acc;
    __syncthreads();
    if (threadIdx.x == 0) out[0] = (sm[0] + sm[1] + sm[2] + sm[3]) * inv_npix;
}

extern "C" void kernel_launch(void* const* d_in, const int* in_sizes, int n_in,
                              void* d_out, int out_size, void* d_ws, size_t ws_size,
                              hipStream_t stream) {
    const float4* gen = (const float4*)d_in[0];  // genImage
    const float4* gt  = (const float4*)d_in[1];  // gtImage

    const int total_f = in_sizes[0];             // 25,165,824 floats
    const int ntrip   = total_f / 12;            // 4-pixel work items
    const int npix    = total_f / 3;

    float* partial = (float*)d_ws;
    const int blocks  = 2048;
    const int threads = blocks * 256;

    if (ntrip == threads * 4) {
        de_main_fix<4><<<blocks, 256, 0, stream>>>(gen, gt, partial, threads);
        de_final<<<1, 256, 0, stream>>>(partial, (float*)d_out,
                                        blocks, 1.0f / (float)npix);
    } else {
        de_main_gen<<<blocks, 256, 0, stream>>>(gen, gt, partial, ntrip);
        de_final<<<1, 256, 0, stream>>>(partial, (float*)d_out,
                                        blocks, 1.0f / (float)npix);
    }
}